// Round 5
// baseline (349.267 us; speedup 1.0000x reference)
//
#include <hip/hip_runtime.h>
#include <math.h>

// Problem constants (match reference)
constexpr int N_ROWS = 100000;   // outputSize
constexpr int D      = 128;      // feature dim
constexpr int B      = 128;      // batch
constexpr int KP1    = 4097;     // K+1
constexpr int TOTAL_PAIRS = B * KP1;            // 524,416
constexpr float INV_T = 1.0f / 0.07f;
constexpr int N4 = N_ROWS * (D / 4);            // float4 per bank: 3.2M

constexpr int SCAN_BLOCKS = (N_ROWS + 255) / 256;   // 391
constexpr int FUSE_BLOCKS = 2048;
constexpr int NGROUPS     = FUSE_BLOCKS * 8;        // 32-lane groups in fused pass

// workspace layout (bytes): [0]=sums(2f,pad16) [16]=offs[100k] [400016]=cursor[100k]
// [800016]=btot[512] [802064]=plist[524416] -> total 2,899,728
constexpr size_t WS_OFFS   = 16;
constexpr size_t WS_CURSOR = WS_OFFS + (size_t)N_ROWS * 4;
constexpr size_t WS_BTOT   = WS_CURSOR + (size_t)N_ROWS * 4;
constexpr size_t WS_PLIST  = WS_BTOT + 512 * 4;
constexpr size_t WS_NEEDED = WS_PLIST + (size_t)TOTAL_PAIRS * 4;

typedef float fvec4 __attribute__((ext_vector_type(4)));  // nontemporal-store-safe

// ---------------------------------------------------------------------------
__device__ __forceinline__ float dot4(float4 a, float4 b) {
    return a.x * b.x + a.y * b.y + a.z * b.z + a.w * b.w;
}
// xor-butterfly over the 32-lane group: leaves the full sum in ALL lanes
__device__ __forceinline__ float red32(float v) {
    #pragma unroll
    for (int off = 16; off >= 1; off >>= 1) v += __shfl_xor(v, off);
    return v;
}

// ===========================================================================
// CSR binning: pairs sorted by bank row so the fused pass streams each row once.
// ===========================================================================
__global__ __launch_bounds__(256) void zero_ws_kernel(float* sums, int* offs) {
    int i = blockIdx.x * 256 + threadIdx.x;
    if (i < 2) sums[i] = 0.0f;
    for (int j = i; j < N_ROWS; j += gridDim.x * 256) offs[j] = 0;
}

__global__ __launch_bounds__(256) void hist_kernel(
    const int* __restrict__ idx, int* __restrict__ offs) {
    int stride = gridDim.x * 256;
    for (int p = blockIdx.x * 256 + threadIdx.x; p < TOTAL_PAIRS; p += stride)
        atomicAdd(&offs[idx[p]], 1);
}

// in-place per-256-block exclusive scan; block totals to btot
__global__ __launch_bounds__(256) void scan_block_kernel(
    int* __restrict__ offs, int* __restrict__ btot) {
    __shared__ int buf[256];
    const int t = threadIdx.x;
    const int i = blockIdx.x * 256 + t;
    int v = (i < N_ROWS) ? offs[i] : 0;
    buf[t] = v;
    __syncthreads();
    for (int off = 1; off < 256; off <<= 1) {
        int y = (t >= off) ? buf[t - off] : 0;
        __syncthreads();
        buf[t] += y;
        __syncthreads();
    }
    if (i < N_ROWS) offs[i] = buf[t] - v;        // exclusive within block
    if (t == 255) btot[blockIdx.x] = buf[t];     // inclusive block total
}

// single-block exclusive scan of the 391 block totals (in place)
__global__ void scan_btot_kernel(int* __restrict__ btot) {
    __shared__ int buf[512];
    const int t = threadIdx.x;
    int v = (t < SCAN_BLOCKS) ? btot[t] : 0;
    buf[t] = v;
    __syncthreads();
    for (int off = 1; off < 512; off <<= 1) {
        int y = (t >= off) ? buf[t - off] : 0;
        __syncthreads();
        buf[t] += y;
        __syncthreads();
    }
    if (t < SCAN_BLOCKS) btot[t] = buf[t] - v;   // exclusive
}

__global__ __launch_bounds__(256) void addback_kernel(
    int* __restrict__ offs, const int* __restrict__ btot, int* __restrict__ cursor) {
    int i = blockIdx.x * 256 + threadIdx.x;
    if (i < N_ROWS) {
        int o = offs[i] + btot[i >> 8];
        offs[i] = o;                              // start offset (kept)
        cursor[i] = o;                            // atomic cursor (becomes end)
    }
}

__global__ __launch_bounds__(256) void scatter_kernel(
    const int* __restrict__ idx, int* __restrict__ cursor, int* __restrict__ plist) {
    int stride = gridDim.x * 256;
    for (int p = blockIdx.x * 256 + threadIdx.x; p < TOTAL_PAIRS; p += stride) {
        int r = idx[p];
        int pos = atomicAdd(&cursor[r], 1);
        plist[pos] = p;
    }
}

// ===========================================================================
// Fused pass: stream both banks ONCE. Per row: 32-lane group holds the row's
// float4 fragments in registers, nt-stores them to o1/o2 (the copy), then
// computes dot/exp for every pair referencing the row (CSR list). v1/v2 are
// 128 KB -> L2-hot gathers. After scatter, cursor[r] == end offset.
// ===========================================================================
__global__ __launch_bounds__(256) void fused_kernel(
    const float* __restrict__ v1, const float* __restrict__ v2,
    const float* __restrict__ mem1, const float* __restrict__ mem2,
    const int* __restrict__ offs, const int* __restrict__ cend,
    const int* __restrict__ plist,
    float* __restrict__ out, float* __restrict__ sums,
    float* __restrict__ o1, float* __restrict__ o2)
{
    __shared__ float s1[8], s2[8];
    const int tid = threadIdx.x;
    const int l   = tid & 31;
    const int grp = tid >> 5;
    const int g   = blockIdx.x * 8 + grp;

    const float4* __restrict__ m1 = (const float4*)mem1;
    const float4* __restrict__ m2 = (const float4*)mem2;
    const float4* __restrict__ V1 = (const float4*)v1;
    const float4* __restrict__ V2 = (const float4*)v2;
    fvec4* __restrict__ d1 = (fvec4*)o1;
    fvec4* __restrict__ d2 = (fvec4*)o2;

    float acc1 = 0.0f, acc2 = 0.0f;               // uniform across the group

    for (int r = g; r < N_ROWS; r += NGROUPS) {
        float4 w1 = m1[(size_t)r * 32 + l];
        float4 w2 = m2[(size_t)r * 32 + l];

        fvec4 x1 = {w1.x, w1.y, w1.z, w1.w};
        fvec4 x2 = {w2.x, w2.y, w2.z, w2.w};
        __builtin_nontemporal_store(x1, &d1[(size_t)r * 32 + l]);
        __builtin_nontemporal_store(x2, &d2[(size_t)r * 32 + l]);

        int q = offs[r];
        const int e = cend[r];
        for (; q + 1 < e; q += 2) {               // 2-pair unroll: 4 v-gathers in flight
            int p0 = plist[q], p1 = plist[q + 1];
            int b0 = p0 / KP1, b1 = p1 / KP1;
            float4 a10 = V1[b0 * 32 + l], a20 = V2[b0 * 32 + l];
            float4 a11 = V1[b1 * 32 + l], a21 = V2[b1 * 32 + l];
            float dA0 = red32(dot4(w2, a10));     // out_v1 = mem2 . v1
            float dB0 = red32(dot4(w1, a20));     // out_v2 = mem1 . v2
            float dA1 = red32(dot4(w2, a11));
            float dB1 = red32(dot4(w1, a21));
            float eA0 = __expf(dA0 * INV_T), eB0 = __expf(dB0 * INV_T);
            float eA1 = __expf(dA1 * INV_T), eB1 = __expf(dB1 * INV_T);
            acc1 += eA0 + eA1;
            acc2 += eB0 + eB1;
            if (l == 0) {
                out[p0] = eA0; out[TOTAL_PAIRS + p0] = eB0;
                out[p1] = eA1; out[TOTAL_PAIRS + p1] = eB1;
            }
        }
        if (q < e) {
            int p0 = plist[q];
            int b0 = p0 / KP1;
            float4 a10 = V1[b0 * 32 + l], a20 = V2[b0 * 32 + l];
            float dA0 = red32(dot4(w2, a10));
            float dB0 = red32(dot4(w1, a20));
            float eA0 = __expf(dA0 * INV_T), eB0 = __expf(dB0 * INV_T);
            acc1 += eA0;
            acc2 += eB0;
            if (l == 0) { out[p0] = eA0; out[TOTAL_PAIRS + p0] = eB0; }
        }
    }

    if (l == 0) { s1[grp] = acc1; s2[grp] = acc2; }
    __syncthreads();
    if (tid == 0) {
        float t1 = 0.0f, t2 = 0.0f;
        #pragma unroll
        for (int i = 0; i < 8; ++i) { t1 += s1[i]; t2 += s2[i]; }
        atomicAdd(&sums[0], t1);
        atomicAdd(&sums[1], t2);
    }
}

// ---------------------------------------------------------------------------
// Finish: scale scores by 1/Z + overwrite y-rows of the copied banks with
// normalize(0.5*mem + 0.5*v). Stream-ordered after fused_kernel.
__global__ __launch_bounds__(256) void finish_kernel(
    float* __restrict__ out, const float* __restrict__ sums,
    const float* __restrict__ v1, const float* __restrict__ v2,
    const int* __restrict__ y,
    const float* __restrict__ mem1, const float* __restrict__ mem2,
    float* __restrict__ o1, float* __restrict__ o2)
{
    if (blockIdx.x < 2 * B && threadIdx.x < 64) {
        int b    = blockIdx.x & (B - 1);
        int bank = blockIdx.x >> 7;
        int lane = threadIdx.x;
        const float2* __restrict__ m = (const float2*)(bank ? mem2 : mem1);
        const float2* __restrict__ v = (const float2*)(bank ? v2 : v1);
        float2* __restrict__ o       = (float2*)(bank ? o2 : o1);
        int row = y[b];
        float2 mv = m[(size_t)row * 64 + lane];
        float2 vv = v[b * 64 + lane];
        float2 u;
        u.x = 0.5f * mv.x + 0.5f * vv.x;
        u.y = 0.5f * mv.y + 0.5f * vv.y;
        float ss = u.x * u.x + u.y * u.y;
        #pragma unroll
        for (int off = 32; off >= 1; off >>= 1) ss += __shfl_xor(ss, off);
        float inv = 1.0f / sqrtf(ss);
        float2 r; r.x = u.x * inv; r.y = u.y * inv;
        o[(size_t)row * 64 + lane] = r;
    }

    float sc1 = (float)((double)TOTAL_PAIRS / ((double)sums[0] * (double)N_ROWS));
    float sc2 = (float)((double)TOTAL_PAIRS / ((double)sums[1] * (double)N_ROWS));
    int stride = gridDim.x * blockDim.x;
    for (int i = blockIdx.x * blockDim.x + threadIdx.x; i < 2 * TOTAL_PAIRS;
         i += stride) {
        out[i] *= (i < TOTAL_PAIRS) ? sc1 : sc2;
    }
}

// ===========================================================================
// Fallback path (ws too small for CSR): round-3 structure.
// ===========================================================================
__global__ void init_ws_kernel(float* ws) {
    if (threadIdx.x < 2) ws[threadIdx.x] = 0.0f;
}

__global__ __launch_bounds__(256) void score_kernel(
    const float* __restrict__ v1, const float* __restrict__ v2,
    const int* __restrict__ idx,
    const float* __restrict__ mem1, const float* __restrict__ mem2,
    float* __restrict__ out, float* __restrict__ sums)
{
    __shared__ alignas(16) int s_idx[260];
    __shared__ float s1[8], s2[8];
    const int sid   = blockIdx.x;
    const int tid   = threadIdx.x;
    const int l     = tid & 31;
    const int grp   = tid >> 5;
    const int b     = sid >> 4;
    const int chunk = sid & 15;
    const int cnt   = (chunk == 15) ? 257 : 256;
    const int ibase = b * KP1 + chunk * 256;
    for (int t = tid; t < cnt; t += 256) s_idx[t] = idx[ibase + t];
    __syncthreads();
    const float4* __restrict__ m1 = (const float4*)mem1;
    const float4* __restrict__ m2 = (const float4*)mem2;
    const float4 a1 = ((const float4*)v1)[b * 32 + l];
    const float4 a2 = ((const float4*)v2)[b * 32 + l];
    const int lk = grp * 32, pbase = ibase + lk;
    float acc1 = 0.0f, acc2 = 0.0f;
    for (int u = 0; u < 32; u += 4) {
        const int4 rr = *(const int4*)&s_idx[lk + u];
        float4 wA0 = m2[(size_t)rr.x * 32 + l], wB0 = m1[(size_t)rr.x * 32 + l];
        float4 wA1 = m2[(size_t)rr.y * 32 + l], wB1 = m1[(size_t)rr.y * 32 + l];
        float4 wA2 = m2[(size_t)rr.z * 32 + l], wB2 = m1[(size_t)rr.z * 32 + l];
        float4 wA3 = m2[(size_t)rr.w * 32 + l], wB3 = m1[(size_t)rr.w * 32 + l];
        float eA0 = __expf(red32(dot4(wA0, a1)) * INV_T);
        float eB0 = __expf(red32(dot4(wB0, a2)) * INV_T);
        float eA1 = __expf(red32(dot4(wA1, a1)) * INV_T);
        float eB1 = __expf(red32(dot4(wB1, a2)) * INV_T);
        float eA2 = __expf(red32(dot4(wA2, a1)) * INV_T);
        float eB2 = __expf(red32(dot4(wB2, a2)) * INV_T);
        float eA3 = __expf(red32(dot4(wA3, a1)) * INV_T);
        float eB3 = __expf(red32(dot4(wB3, a2)) * INV_T);
        acc1 += (eA0 + eA1) + (eA2 + eA3);
        acc2 += (eB0 + eB1) + (eB2 + eB3);
        float sa = (l & 1) ? eA1 : eA0, sb = (l & 1) ? eA3 : eA2;
        float evA = (l & 2) ? sb : sa;
        float sc = (l & 1) ? eB1 : eB0, sd = (l & 1) ? eB3 : eB2;
        float evB = (l & 2) ? sd : sc;
        int p = pbase + u;
        if (l < 4)      out[p + l] = evA;
        else if (l < 8) out[TOTAL_PAIRS + p + (l - 4)] = evB;
    }
    if (chunk == 15 && grp == 7) {
        int r = s_idx[256];
        float4 wA = m2[(size_t)r * 32 + l], wB = m1[(size_t)r * 32 + l];
        float eA = __expf(red32(dot4(wA, a1)) * INV_T);
        float eB = __expf(red32(dot4(wB, a2)) * INV_T);
        acc1 += eA; acc2 += eB;
        if (l == 0) {
            out[b * KP1 + 4096] = eA;
            out[TOTAL_PAIRS + b * KP1 + 4096] = eB;
        }
    }
    if (l == 0) { s1[grp] = acc1; s2[grp] = acc2; }
    __syncthreads();
    if (tid == 0) {
        float t1 = 0.0f, t2 = 0.0f;
        #pragma unroll
        for (int i = 0; i < 8; ++i) { t1 += s1[i]; t2 += s2[i]; }
        atomicAdd(&sums[0], t1);
        atomicAdd(&sums[1], t2);
    }
}

__global__ __launch_bounds__(256) void copy_scale_kernel(
    const float* __restrict__ mem1, const float* __restrict__ mem2,
    float* __restrict__ o1, float* __restrict__ o2,
    float* __restrict__ out, const float* __restrict__ sums)
{
    const fvec4* __restrict__ m1 = (const fvec4*)mem1;
    const fvec4* __restrict__ m2 = (const fvec4*)mem2;
    fvec4* __restrict__ d1 = (fvec4*)o1;
    fvec4* __restrict__ d2 = (fvec4*)o2;
    int tid = blockIdx.x * 256 + threadIdx.x;
    int stride = gridDim.x * 256;
    for (int i = tid; i < N4; i += stride) {
        fvec4 x1 = m1[i], x2 = m2[i];
        __builtin_nontemporal_store(x1, &d1[i]);
        __builtin_nontemporal_store(x2, &d2[i]);
    }
    float sc1 = (float)((double)TOTAL_PAIRS / ((double)sums[0] * (double)N_ROWS));
    float sc2 = (float)((double)TOTAL_PAIRS / ((double)sums[1] * (double)N_ROWS));
    for (int i = tid; i < 2 * TOTAL_PAIRS; i += stride) {
        out[i] *= (i < TOTAL_PAIRS) ? sc1 : sc2;
    }
}

__global__ void rowupd_kernel(
    const float* __restrict__ v1, const float* __restrict__ v2,
    const int* __restrict__ y,
    const float* __restrict__ mem1, const float* __restrict__ mem2,
    float* __restrict__ o1, float* __restrict__ o2)
{
    int b    = blockIdx.x & (B - 1);
    int bank = blockIdx.x >> 7;
    int lane = threadIdx.x;
    const float2* __restrict__ m = (const float2*)(bank ? mem2 : mem1);
    const float2* __restrict__ v = (const float2*)(bank ? v2 : v1);
    float2* __restrict__ o       = (float2*)(bank ? o2 : o1);
    int row = y[b];
    float2 mv = m[(size_t)row * 64 + lane];
    float2 vv = v[b * 64 + lane];
    float2 u;
    u.x = 0.5f * mv.x + 0.5f * vv.x;
    u.y = 0.5f * mv.y + 0.5f * vv.y;
    float ss = u.x * u.x + u.y * u.y;
    #pragma unroll
    for (int off = 32; off >= 1; off >>= 1) ss += __shfl_xor(ss, off);
    float inv = 1.0f / sqrtf(ss);
    float2 r; r.x = u.x * inv; r.y = u.y * inv;
    o[(size_t)row * 64 + lane] = r;
}

// ---------------------------------------------------------------------------
extern "C" void kernel_launch(void* const* d_in, const int* in_sizes, int n_in,
                              void* d_out, int out_size, void* d_ws, size_t ws_size,
                              hipStream_t stream) {
    const float* v1   = (const float*)d_in[0];
    const float* v2   = (const float*)d_in[1];
    const int*   idx  = (const int*)d_in[2];
    const int*   y    = (const int*)d_in[3];
    const float* mem1 = (const float*)d_in[4];
    const float* mem2 = (const float*)d_in[5];

    float* out = (float*)d_out;
    float* out_mem1 = out + 2 * (size_t)TOTAL_PAIRS;
    float* out_mem2 = out_mem1 + (size_t)N_ROWS * D;
    char*  ws   = (char*)d_ws;
    float* sums = (float*)d_ws;

    if (ws_size >= WS_NEEDED) {
        int* offs   = (int*)(ws + WS_OFFS);
        int* cursor = (int*)(ws + WS_CURSOR);
        int* btot   = (int*)(ws + WS_BTOT);
        int* plist  = (int*)(ws + WS_PLIST);

        zero_ws_kernel<<<256, 256, 0, stream>>>(sums, offs);
        hist_kernel<<<512, 256, 0, stream>>>(idx, offs);
        scan_block_kernel<<<SCAN_BLOCKS, 256, 0, stream>>>(offs, btot);
        scan_btot_kernel<<<1, 512, 0, stream>>>(btot);
        addback_kernel<<<SCAN_BLOCKS, 256, 0, stream>>>(offs, btot, cursor);
        scatter_kernel<<<512, 256, 0, stream>>>(idx, cursor, plist);
        fused_kernel<<<FUSE_BLOCKS, 256, 0, stream>>>(
            v1, v2, mem1, mem2, offs, cursor, plist,
            out, sums, out_mem1, out_mem2);
        finish_kernel<<<1024, 256, 0, stream>>>(
            out, sums, v1, v2, y, mem1, mem2, out_mem1, out_mem2);
    } else {
        // fallback: round-3 structure (needs only 8 B of ws)
        init_ws_kernel<<<1, 64, 0, stream>>>(sums);
        score_kernel<<<2048, 256, 0, stream>>>(
            v1, v2, idx, mem1, mem2, out, sums);
        copy_scale_kernel<<<2048, 256, 0, stream>>>(
            mem1, mem2, out_mem1, out_mem2, out, sums);
        rowupd_kernel<<<2 * B, 64, 0, stream>>>(
            v1, v2, y, mem1, mem2, out_mem1, out_mem2);
    }
}

// Round 6
// 314.565 us; speedup vs baseline: 1.1103x; 1.1103x over previous
//
#include <hip/hip_runtime.h>
#include <math.h>

// Problem constants (match reference)
constexpr int N_ROWS = 100000;   // outputSize
constexpr int D      = 128;      // feature dim
constexpr int B      = 128;      // batch
constexpr int KP1    = 4097;     // K+1
constexpr int TOTAL_PAIRS = B * KP1;            // 524,416
constexpr float INV_T = 1.0f / 0.07f;
constexpr int N4 = N_ROWS * (D / 4);            // float4 per bank: 3.2M

// Bucketed CSR: 40 rows per bucket -> 2500 buckets; block k owns bucket k,
// stages its 40 rows of BOTH banks in LDS (sequential, coalesced), then
// 8-lane teams compute all pairs touching those rows with lane-local dots.
constexpr int RPB  = 40;
constexpr int NB   = N_ROWS / RPB;              // 2500 (exact)
constexpr int PADR = 33;                        // float4 stride per row in LDS

// workspace layout (bytes):
//   [0)      sums: 2 floats (zeroed by memset)
//   [64)     bcnt_padded: NB counters, one per 64B line (16 ints) -> 160,000 B
//   [160064) bstart: NB+1 ints (+pad)
//   [170080) plist: TOTAL_PAIRS u32 (p | lr<<20)
constexpr size_t WS_BCNT   = 64;
constexpr size_t WS_BSTART = WS_BCNT + (size_t)NB * 16 * 4;          // 160064
constexpr size_t WS_PLIST  = WS_BSTART + (size_t)(NB + 4) * 4;       // 170080
constexpr size_t WS_NEEDED = WS_PLIST + (size_t)TOTAL_PAIRS * 4;     // ~2.27 MB
constexpr size_t WS_ZERO_BYTES = WS_BSTART;                          // sums+bcnt

typedef float fvec4 __attribute__((ext_vector_type(4)));  // nontemporal-store-safe

// ---------------------------------------------------------------------------
__device__ __forceinline__ float dot4(float4 a, float4 b) {
    return a.x * b.x + a.y * b.y + a.z * b.z + a.w * b.w;
}
__device__ __forceinline__ float red32(float v) {
    #pragma unroll
    for (int off = 16; off >= 1; off >>= 1) v += __shfl_xor(v, off);
    return v;
}

// ===========================================================================
// Prep: bucket histogram -> scan -> scatter (plist packed p | lr<<20)
// ===========================================================================
__global__ __launch_bounds__(256) void hist_kernel(
    const int* __restrict__ idx, int* __restrict__ bcnt) {
    int stride = gridDim.x * 256;
    for (int p = blockIdx.x * 256 + threadIdx.x; p < TOTAL_PAIRS; p += stride) {
        int bkt = idx[p] / RPB;
        atomicAdd(&bcnt[bkt * 16], 1);
    }
}

// single block, 1024 threads: exclusive scan of NB padded counts.
// writes bstart[0..NB] and resets bcnt[k*16] to the start (scatter cursor).
__global__ __launch_bounds__(1024) void scan_kernel(
    int* __restrict__ bcnt, int* __restrict__ bstart) {
    __shared__ int ssum[1024];
    const int t = threadIdx.x;
    const int b0 = 3 * t;
    int c0 = (b0     < NB) ? bcnt[(b0    ) * 16] : 0;
    int c1 = (b0 + 1 < NB) ? bcnt[(b0 + 1) * 16] : 0;
    int c2 = (b0 + 2 < NB) ? bcnt[(b0 + 2) * 16] : 0;
    int local = c0 + c1 + c2;
    ssum[t] = local;
    __syncthreads();
    for (int off = 1; off < 1024; off <<= 1) {
        int v = (t >= off) ? ssum[t - off] : 0;
        __syncthreads();
        ssum[t] += v;
        __syncthreads();
    }
    int excl = ssum[t] - local;
    if (b0     < NB) { bstart[b0]     = excl;           bcnt[(b0    ) * 16] = excl; }
    if (b0 + 1 < NB) { bstart[b0 + 1] = excl + c0;      bcnt[(b0 + 1) * 16] = excl + c0; }
    if (b0 + 2 < NB) { bstart[b0 + 2] = excl + c0 + c1; bcnt[(b0 + 2) * 16] = excl + c0 + c1; }
    if (t == 1023) bstart[NB] = ssum[1023];
}

__global__ __launch_bounds__(256) void scatter_kernel(
    const int* __restrict__ idx, int* __restrict__ bcnt,
    unsigned* __restrict__ plist) {
    int stride = gridDim.x * 256;
    for (int p = blockIdx.x * 256 + threadIdx.x; p < TOTAL_PAIRS; p += stride) {
        int r   = idx[p];
        int bkt = r / RPB;
        int lr  = r - bkt * RPB;
        int pos = atomicAdd(&bcnt[bkt * 16], 1);
        plist[pos] = (unsigned)p | ((unsigned)lr << 20);
    }
}

// ===========================================================================
// Fused: block k streams rows [k*RPB, k*RPB+RPB) of both banks into LDS
// (coalesced) and nt-stores them to o1/o2 (the copy). Then 8-lane teams
// process the bucket's pairs: row from LDS (lane-local 4 chunks), v from
// L1/L2 (128 B contiguous per team), 3-shuffle reduce, exp, store.
// ===========================================================================
__global__ __launch_bounds__(256) void fused_kernel(
    const float* __restrict__ v1, const float* __restrict__ v2,
    const float* __restrict__ mem1, const float* __restrict__ mem2,
    const int* __restrict__ bstart, const unsigned* __restrict__ plist,
    float* __restrict__ out, float* __restrict__ sums,
    float* __restrict__ o1, float* __restrict__ o2)
{
    __shared__ float4 sm1[RPB * PADR];   // 21,120 B
    __shared__ float4 sm2[RPB * PADR];   // 21,120 B
    __shared__ float sz1[4], sz2[4];

    const int bid = blockIdx.x;
    const int tid = threadIdx.x;
    const int r0  = bid * RPB;

    const float4* __restrict__ M1 = (const float4*)mem1;
    const float4* __restrict__ M2 = (const float4*)mem2;
    const float4* __restrict__ V1 = (const float4*)v1;
    const float4* __restrict__ V2 = (const float4*)v2;
    fvec4* __restrict__ d1 = (fvec4*)o1;
    fvec4* __restrict__ d2 = (fvec4*)o2;

    // ---- stage rows (sequential, coalesced) + fused copy ----
    for (int i = tid; i < RPB * 32; i += 256) {
        int lr = i >> 5, c = i & 31;
        size_t gi = (size_t)(r0 + lr) * 32 + c;
        float4 x1 = M1[gi];
        float4 x2 = M2[gi];
        sm1[lr * PADR + c] = x1;
        sm2[lr * PADR + c] = x2;
        fvec4 y1 = {x1.x, x1.y, x1.z, x1.w};
        fvec4 y2 = {x2.x, x2.y, x2.z, x2.w};
        __builtin_nontemporal_store(y1, &d1[gi]);
        __builtin_nontemporal_store(y2, &d2[gi]);
    }
    __syncthreads();

    // ---- pair phase: 8-lane teams ----
    const int team = tid >> 3;             // 0..31
    const int sub  = tid & 7;              // lane within team
    const int qend = bstart[bid + 1];
    float az1 = 0.0f, az2 = 0.0f;          // each team-lane accumulates (x8)

    for (int q = bstart[bid] + team; q < qend; q += 32) {
        unsigned v = plist[q];
        int p  = (int)(v & 0xFFFFFu);
        int lr = (int)(v >> 20);
        int b  = p / KP1;                  // magic-mul

        const float4* __restrict__ w1 = &sm1[lr * PADR];
        const float4* __restrict__ w2 = &sm2[lr * PADR];
        float a = 0.0f, bb = 0.0f;
        #pragma unroll
        for (int i = 0; i < 4; ++i) {
            int c = sub + 8 * i;
            float4 vv1 = V1[b * 32 + c];
            float4 vv2 = V2[b * 32 + c];
            float4 x2  = w2[c];
            float4 x1  = w1[c];
            a  += dot4(x2, vv1);           // out_v1 = mem2 . v1
            bb += dot4(x1, vv2);           // out_v2 = mem1 . v2
        }
        #pragma unroll
        for (int off = 4; off >= 1; off >>= 1) {
            a  += __shfl_xor(a,  off);
            bb += __shfl_xor(bb, off);
        }
        float eA = __expf(a  * INV_T);
        float eB = __expf(bb * INV_T);
        az1 += eA;                          // all 8 lanes: /8 at the end
        az2 += eB;
        if (sub < 2) out[(sub ? TOTAL_PAIRS : 0) + p] = sub ? eB : eA;
    }

    // ---- block Z reduction (x1/8 compensation) ----
    #pragma unroll
    for (int off = 32; off >= 1; off >>= 1) {
        az1 += __shfl_xor(az1, off);
        az2 += __shfl_xor(az2, off);
    }
    if ((tid & 63) == 0) { sz1[tid >> 6] = az1; sz2[tid >> 6] = az2; }
    __syncthreads();
    if (tid == 0) {
        float t1 = (sz1[0] + sz1[1] + sz1[2] + sz1[3]) * 0.125f;
        float t2 = (sz2[0] + sz2[1] + sz2[2] + sz2[3]) * 0.125f;
        atomicAdd(&sums[0], t1);
        atomicAdd(&sums[1], t2);
    }
}

// ---------------------------------------------------------------------------
// Finish: scale scores by 1/Z + overwrite y-rows of the copied banks with
// normalize(0.5*mem + 0.5*v). Stream-ordered after fused_kernel.
__global__ __launch_bounds__(256) void finish_kernel(
    float* __restrict__ out, const float* __restrict__ sums,
    const float* __restrict__ v1, const float* __restrict__ v2,
    const int* __restrict__ y,
    const float* __restrict__ mem1, const float* __restrict__ mem2,
    float* __restrict__ o1, float* __restrict__ o2)
{
    if (blockIdx.x < 2 * B && threadIdx.x < 64) {
        int b    = blockIdx.x & (B - 1);
        int bank = blockIdx.x >> 7;
        int lane = threadIdx.x;
        const float2* __restrict__ m = (const float2*)(bank ? mem2 : mem1);
        const float2* __restrict__ v = (const float2*)(bank ? v2 : v1);
        float2* __restrict__ o       = (float2*)(bank ? o2 : o1);
        int row = y[b];
        float2 mv = m[(size_t)row * 64 + lane];
        float2 vv = v[b * 64 + lane];
        float2 u;
        u.x = 0.5f * mv.x + 0.5f * vv.x;
        u.y = 0.5f * mv.y + 0.5f * vv.y;
        float ss = u.x * u.x + u.y * u.y;
        #pragma unroll
        for (int off = 32; off >= 1; off >>= 1) ss += __shfl_xor(ss, off);
        float inv = 1.0f / sqrtf(ss);
        float2 r; r.x = u.x * inv; r.y = u.y * inv;
        o[(size_t)row * 64 + lane] = r;
    }

    float sc1 = (float)((double)TOTAL_PAIRS / ((double)sums[0] * (double)N_ROWS));
    float sc2 = (float)((double)TOTAL_PAIRS / ((double)sums[1] * (double)N_ROWS));
    int stride = gridDim.x * blockDim.x;
    for (int i = blockIdx.x * blockDim.x + threadIdx.x; i < 2 * TOTAL_PAIRS;
         i += stride) {
        out[i] *= (i < TOTAL_PAIRS) ? sc1 : sc2;
    }
}

// ===========================================================================
// Fallback path (ws too small): round-3 structure.
// ===========================================================================
__global__ void init_ws_kernel(float* ws) {
    if (threadIdx.x < 2) ws[threadIdx.x] = 0.0f;
}

__global__ __launch_bounds__(256) void score_kernel(
    const float* __restrict__ v1, const float* __restrict__ v2,
    const int* __restrict__ idx,
    const float* __restrict__ mem1, const float* __restrict__ mem2,
    float* __restrict__ out, float* __restrict__ sums)
{
    __shared__ alignas(16) int s_idx[260];
    __shared__ float s1[8], s2[8];
    const int sid   = blockIdx.x;
    const int tid   = threadIdx.x;
    const int l     = tid & 31;
    const int grp   = tid >> 5;
    const int b     = sid >> 4;
    const int chunk = sid & 15;
    const int cnt   = (chunk == 15) ? 257 : 256;
    const int ibase = b * KP1 + chunk * 256;
    for (int t = tid; t < cnt; t += 256) s_idx[t] = idx[ibase + t];
    __syncthreads();
    const float4* __restrict__ m1 = (const float4*)mem1;
    const float4* __restrict__ m2 = (const float4*)mem2;
    const float4 a1 = ((const float4*)v1)[b * 32 + l];
    const float4 a2 = ((const float4*)v2)[b * 32 + l];
    const int lk = grp * 32, pbase = ibase + lk;
    float acc1 = 0.0f, acc2 = 0.0f;
    for (int u = 0; u < 32; u += 4) {
        const int4 rr = *(const int4*)&s_idx[lk + u];
        float4 wA0 = m2[(size_t)rr.x * 32 + l], wB0 = m1[(size_t)rr.x * 32 + l];
        float4 wA1 = m2[(size_t)rr.y * 32 + l], wB1 = m1[(size_t)rr.y * 32 + l];
        float4 wA2 = m2[(size_t)rr.z * 32 + l], wB2 = m1[(size_t)rr.z * 32 + l];
        float4 wA3 = m2[(size_t)rr.w * 32 + l], wB3 = m1[(size_t)rr.w * 32 + l];
        float eA0 = __expf(red32(dot4(wA0, a1)) * INV_T);
        float eB0 = __expf(red32(dot4(wB0, a2)) * INV_T);
        float eA1 = __expf(red32(dot4(wA1, a1)) * INV_T);
        float eB1 = __expf(red32(dot4(wB1, a2)) * INV_T);
        float eA2 = __expf(red32(dot4(wA2, a1)) * INV_T);
        float eB2 = __expf(red32(dot4(wB2, a2)) * INV_T);
        float eA3 = __expf(red32(dot4(wA3, a1)) * INV_T);
        float eB3 = __expf(red32(dot4(wB3, a2)) * INV_T);
        acc1 += (eA0 + eA1) + (eA2 + eA3);
        acc2 += (eB0 + eB1) + (eB2 + eB3);
        float sa = (l & 1) ? eA1 : eA0, sb = (l & 1) ? eA3 : eA2;
        float evA = (l & 2) ? sb : sa;
        float sc = (l & 1) ? eB1 : eB0, sd = (l & 1) ? eB3 : eB2;
        float evB = (l & 2) ? sd : sc;
        int p = pbase + u;
        if (l < 4)      out[p + l] = evA;
        else if (l < 8) out[TOTAL_PAIRS + p + (l - 4)] = evB;
    }
    if (chunk == 15 && grp == 7) {
        int r = s_idx[256];
        float4 wA = m2[(size_t)r * 32 + l], wB = m1[(size_t)r * 32 + l];
        float eA = __expf(red32(dot4(wA, a1)) * INV_T);
        float eB = __expf(red32(dot4(wB, a2)) * INV_T);
        acc1 += eA; acc2 += eB;
        if (l == 0) {
            out[b * KP1 + 4096] = eA;
            out[TOTAL_PAIRS + b * KP1 + 4096] = eB;
        }
    }
    if (l == 0) { s1[grp] = acc1; s2[grp] = acc2; }
    __syncthreads();
    if (tid == 0) {
        float t1 = 0.0f, t2 = 0.0f;
        #pragma unroll
        for (int i = 0; i < 8; ++i) { t1 += s1[i]; t2 += s2[i]; }
        atomicAdd(&sums[0], t1);
        atomicAdd(&sums[1], t2);
    }
}

__global__ __launch_bounds__(256) void copy_scale_kernel(
    const float* __restrict__ mem1, const float* __restrict__ mem2,
    float* __restrict__ o1, float* __restrict__ o2,
    float* __restrict__ out, const float* __restrict__ sums)
{
    const fvec4* __restrict__ m1 = (const fvec4*)mem1;
    const fvec4* __restrict__ m2 = (const fvec4*)mem2;
    fvec4* __restrict__ d1 = (fvec4*)o1;
    fvec4* __restrict__ d2 = (fvec4*)o2;
    int tid = blockIdx.x * 256 + threadIdx.x;
    int stride = gridDim.x * 256;
    for (int i = tid; i < N4; i += stride) {
        fvec4 x1 = m1[i], x2 = m2[i];
        __builtin_nontemporal_store(x1, &d1[i]);
        __builtin_nontemporal_store(x2, &d2[i]);
    }
    float sc1 = (float)((double)TOTAL_PAIRS / ((double)sums[0] * (double)N_ROWS));
    float sc2 = (float)((double)TOTAL_PAIRS / ((double)sums[1] * (double)N_ROWS));
    for (int i = tid; i < 2 * TOTAL_PAIRS; i += stride) {
        out[i] *= (i < TOTAL_PAIRS) ? sc1 : sc2;
    }
}

__global__ void rowupd_kernel(
    const float* __restrict__ v1, const float* __restrict__ v2,
    const int* __restrict__ y,
    const float* __restrict__ mem1, const float* __restrict__ mem2,
    float* __restrict__ o1, float* __restrict__ o2)
{
    int b    = blockIdx.x & (B - 1);
    int bank = blockIdx.x >> 7;
    int lane = threadIdx.x;
    const float2* __restrict__ m = (const float2*)(bank ? mem2 : mem1);
    const float2* __restrict__ v = (const float2*)(bank ? v2 : v1);
    float2* __restrict__ o       = (float2*)(bank ? o2 : o1);
    int row = y[b];
    float2 mv = m[(size_t)row * 64 + lane];
    float2 vv = v[b * 64 + lane];
    float2 u;
    u.x = 0.5f * mv.x + 0.5f * vv.x;
    u.y = 0.5f * mv.y + 0.5f * vv.y;
    float ss = u.x * u.x + u.y * u.y;
    #pragma unroll
    for (int off = 32; off >= 1; off >>= 1) ss += __shfl_xor(ss, off);
    float inv = 1.0f / sqrtf(ss);
    float2 r; r.x = u.x * inv; r.y = u.y * inv;
    o[(size_t)row * 64 + lane] = r;
}

// ---------------------------------------------------------------------------
extern "C" void kernel_launch(void* const* d_in, const int* in_sizes, int n_in,
                              void* d_out, int out_size, void* d_ws, size_t ws_size,
                              hipStream_t stream) {
    const float* v1   = (const float*)d_in[0];
    const float* v2   = (const float*)d_in[1];
    const int*   idx  = (const int*)d_in[2];
    const int*   y    = (const int*)d_in[3];
    const float* mem1 = (const float*)d_in[4];
    const float* mem2 = (const float*)d_in[5];

    float* out = (float*)d_out;
    float* out_mem1 = out + 2 * (size_t)TOTAL_PAIRS;
    float* out_mem2 = out_mem1 + (size_t)N_ROWS * D;
    char*  ws   = (char*)d_ws;
    float* sums = (float*)d_ws;

    if (ws_size >= WS_NEEDED) {
        int*      bcnt   = (int*)(ws + WS_BCNT);
        int*      bstart = (int*)(ws + WS_BSTART);
        unsigned* plist  = (unsigned*)(ws + WS_PLIST);

        hipMemsetAsync(ws, 0, WS_ZERO_BYTES, stream);
        hist_kernel<<<512, 256, 0, stream>>>(idx, bcnt);
        scan_kernel<<<1, 1024, 0, stream>>>(bcnt, bstart);
        scatter_kernel<<<512, 256, 0, stream>>>(idx, bcnt, plist);
        fused_kernel<<<NB, 256, 0, stream>>>(
            v1, v2, mem1, mem2, bstart, plist,
            out, sums, out_mem1, out_mem2);
        finish_kernel<<<1024, 256, 0, stream>>>(
            out, sums, v1, v2, y, mem1, mem2, out_mem1, out_mem2);
    } else {
        // fallback: round-3 structure (needs only 8 B of ws)
        init_ws_kernel<<<1, 64, 0, stream>>>(sums);
        score_kernel<<<2048, 256, 0, stream>>>(
            v1, v2, idx, mem1, mem2, out, sums);
        copy_scale_kernel<<<2048, 256, 0, stream>>>(
            mem1, mem2, out_mem1, out_mem2, out, sums);
        rowupd_kernel<<<2 * B, 64, 0, stream>>>(
            v1, v2, y, mem1, mem2, out_mem1, out_mem2);
    }
}